// Round 13
// baseline (799.132 us; speedup 1.0000x reference)
//
#include <hip/hip_runtime.h>
#include <math.h>

#define DEV __device__ __forceinline__

constexpr int B_   = 2;
constexpr int C_IN = 8;
constexpr int H_   = 64;
constexpr int F_   = 257;
constexpr int T_   = 188;
constexpr int TW   = 96;    // t-columns per block (T split in 2)
constexpr int NFFT = 512;
constexpr int HOP  = 256;
constexpr int LEN  = 48000;
constexpr int PADL = 256;
constexpr int FT   = F_ * T_;
constexpr float EPSV  = 1e-4f;
constexpr float SLOPEV = 0.01f;
constexpr float PI2 = 6.283185307179586f;

typedef __attribute__((ext_vector_type(8))) short short8;
typedef __attribute__((ext_vector_type(4))) short short4v;
typedef __attribute__((ext_vector_type(4))) float float4v;

DEV float lrelu_f(float x) { return x > 0.f ? x : SLOPEV * x; }
DEV float snap_f(float x) {
  if (x >= 0.f && x < EPSV) return EPSV;
  if (x < 0.f && x > -EPSV) return -EPSV;
  return x;
}
DEV float fast_atan(float z) {
  float az = fabsf(z);
  float u = az > 1.f ? __builtin_amdgcn_rcpf(az) : az;
  float u2 = u * u;
  float p = -0.01172120f;
  p = p * u2 + 0.05265332f;
  p = p * u2 - 0.11643287f;
  p = p * u2 + 0.19354346f;
  p = p * u2 - 0.33262347f;
  p = p * u2 + 0.99997726f;
  float r = p * u;
  if (az > 1.f) r = 1.5707963267948966f - r;
  return z < 0.f ? -r : r;
}
DEV float modexp_f(float x) {
  const float em = 148.4131591025766f; // e^5
  return x > 5.f ? (x - 5.f) * em + em : __expf(x);
}
DEV void cexp_f(float tr, float ti, float& er, float& ei) {
  float e = modexp_f(tr) - 1.f;
  float a = ti - 1.f;
  er = e * __cosf(a); ei = e * __sinf(a);
}
DEV float sigmoid_f(float x) { return 1.f / (1.f + __expf(-x)); }

DEV short f2bf(float x) {   // RNE float->bf16
  unsigned u = __float_as_uint(x);
  unsigned r = (u + 0x7fffu + ((u >> 16) & 1u)) >> 16;
  return (short)r;
}
DEV float bf2f(short h) {
  return __uint_as_float(((unsigned)(unsigned short)h) << 16);
}
DEV unsigned pack_hl(float v) {
  short hi = f2bf(v);
  short lo = f2bf(v - bf2f(hi));
  return ((unsigned)(unsigned short)hi << 16) | (unsigned)(unsigned short)lo;
}
DEV float unpack_hl(unsigned v) {
  return bf2f((short)(v >> 16)) + bf2f((short)(v & 0xffffu));
}

// ---------------- mix -> bf16 hi/lo pre-split (staging feed for k_stftmix) --
__global__ void k_mixsplit(const float* __restrict__ x, short* __restrict__ hi,
                           short* __restrict__ lo) {
  int i = blockIdx.x * 256 + threadIdx.x;
  if (i >= B_ * C_IN * LEN / 4) return;
  float4v v = *(const float4v*)(x + (size_t)i * 4);
  short4v h, l;
  #pragma unroll
  for (int j = 0; j < 4; ++j) {
    h[j] = f2bf(v[j]);
    l[j] = f2bf(v[j] - bf2f(h[j]));
  }
  *(short4v*)(hi + (size_t)i * 4) = h;
  *(short4v*)(lo + (size_t)i * 4) = l;
}

// -------- combined (fs_w x windowed-DFT) matrix -> A-fragments hi/lo --------
__global__ __launch_bounds__(256) void k_mixdft(const float* __restrict__ W,
                                                short* __restrict__ wpk) {
  constexpr int MT = 33;
  __shared__ float wr_s[F_], wi_s[F_];
  int m = blockIdx.x;                       // 0..527
  int k = blockIdx.y * 256 + threadIdx.x;   // 0..511
  int po = m >= F_;
  int fo = m - po * F_;
  if (m < 2 * F_) {
    for (int i = threadIdx.x; i < F_; i += 256) {
      wr_s[i] = W[fo * F_ + i];
      wi_s[i] = W[F_ * F_ + fo * F_ + i];
    }
  }
  __syncthreads();
  float val = 0.f;
  if (m < 2 * F_) {
    float sd, cd;
    sincosf((PI2 / NFFT) * k, &sd, &cd);    // step angle 2*pi*k/512
    float cs = 1.f, sn = 0.f;               // fi = 0
    float ar = 0.f, ai = 0.f;
    for (int fi = 0; fi < F_; ++fi) {
      float wrv = wr_s[fi], wiv = wi_s[fi];
      ar += wrv * cs + wiv * sn;
      ai += wiv * cs - wrv * sn;
      float t2 = cs * cd - sn * sd;
      sn = sn * cd + cs * sd;
      cs = t2;
    }
    float win = 0.5f - 0.5f * cd;           // hann(k) reuses cd = cos(2pi k/512)
    val = (po ? ai : ar) * win;
  }
  int mtg = m >> 4;
  int lane2 = ((k >> 3) & 3) * 16 + (m & 15);
  int s = k >> 5;
  int j = k & 7;
  short hi = f2bf(val);
  short lo = f2bf(val - bf2f(hi));
  wpk[(((0 * 16 + s) * MT + mtg) * 64 + lane2) * 8 + j] = hi;
  wpk[(((16 + s) * MT + mtg) * 64 + lane2) * 8 + j] = lo;
}

// ======== fused STFT + freq-mix: ts = M @ frames(mix), hi/lo bf16 MFMA ======
constexpr int TWS = 48;
__global__ __launch_bounds__(256) void k_stftmix(
    const short* __restrict__ mhi, const short* __restrict__ mlo,
    const short* __restrict__ wpk, const float* __restrict__ bias,
    float* __restrict__ Y) {
  constexpr int PITCH = 136;
  constexpr int MT = 33;
  __shared__ short xs_hi[TWS * PITCH];
  __shared__ short xs_lo[TWS * PITCH];
  int mg = blockIdx.x;
  int bc = blockIdx.y;
  int b = bc >> 3, c = bc & 7;
  int t0 = blockIdx.z * TWS;
  int tid = threadIdx.x;
  int lane = tid & 63;
  int wv = __builtin_amdgcn_readfirstlane(tid >> 6);
  int mtg = mg * 4 + wv;
  int q = lane >> 4;
  int n = lane & 15;

  const short* mh_ = mhi + (size_t)(b * C_IN + c) * LEN;
  const short* ml_ = mlo + (size_t)(b * C_IN + c) * LEN;

  float4v acc[3];
  #pragma unroll
  for (int nt = 0; nt < 3; ++nt) acc[nt] = (float4v)(0.f);

  const short8* wp = (const short8*)wpk;
  for (int round = 0; round < 4; ++round) {   // 128 k per round
    if (round) __syncthreads();
    for (int i = tid; i < TWS * 16; i += 256) {
      int tl = i >> 4, u = i & 15;
      int kk0 = u * 8;
      int t = t0 + tl;
      int g0 = t * HOP + round * 128 + kk0 - PADL;
      short8 h, l;
      if (t < T_ && g0 >= 0 && g0 + 7 < LEN) {
        h = *(const short8*)(mh_ + g0);
        l = *(const short8*)(ml_ + g0);
      } else {
        #pragma unroll
        for (int j = 0; j < 8; ++j) {
          short hv = 0, lv = 0;
          if (t < T_) {
            int g = g0 + j;
            if (g < 0) g = -g;
            if (g >= LEN) g = 2 * LEN - 2 - g;
            hv = mh_[g]; lv = ml_[g];
          }
          h[j] = hv; l[j] = lv;
        }
      }
      *(short8*)&xs_hi[tl * PITCH + kk0] = h;
      *(short8*)&xs_lo[tl * PITCH + kk0] = l;
    }
    __syncthreads();
    #pragma unroll
    for (int s2 = 0; s2 < 4; ++s2) {
      int s = round * 4 + s2;
      short8 Ah, Al;
      if (mtg < MT) {
        Ah = wp[((0 * 16 + s) * MT + mtg) * 64 + lane];
        Al = wp[((16 + s) * MT + mtg) * 64 + lane];
      }
      short8 Bh[3], Bl[3];
      #pragma unroll
      for (int nt = 0; nt < 3; ++nt) {
        int off = (nt * 16 + n) * PITCH + s2 * 32 + q * 8;
        Bh[nt] = *(const short8*)&xs_hi[off];
        Bl[nt] = *(const short8*)&xs_lo[off];
      }
      if (mtg < MT) {
        #pragma unroll
        for (int nt = 0; nt < 3; ++nt) {
          acc[nt] = __builtin_amdgcn_mfma_f32_16x16x32_bf16(Ah, Bh[nt], acc[nt], 0, 0, 0);
          acc[nt] = __builtin_amdgcn_mfma_f32_16x16x32_bf16(Ah, Bl[nt], acc[nt], 0, 0, 0);
          acc[nt] = __builtin_amdgcn_mfma_f32_16x16x32_bf16(Al, Bh[nt], acc[nt], 0, 0, 0);
        }
      }
    }
  }

  if (mtg < MT) {
    #pragma unroll
    for (int nt = 0; nt < 3; ++nt) {
      int t = t0 + nt * 16 + n;
      if (t >= T_) continue;
      #pragma unroll
      for (int r = 0; r < 4; ++r) {
        int m = mtg * 16 + q * 4 + r;
        if (m >= 2 * F_) continue;
        int po = m >= F_;
        int fo = m - po * F_;
        float badd = po ? bias[fo] + bias[F_ + fo] : bias[fo] - bias[F_ + fo];
        Y[((size_t)((b * 2 + po) * C_IN + c)) * FT + fo * T_ + t] = acc[nt][r] + badd;
      }
    }
  }
}

// ---------- frequency mixing: complex (F x F) matvec per (b,c,t) ----------
template<int CH>
__global__ void k_fmix(const float* __restrict__ X, const float* __restrict__ W,
                       const float* __restrict__ bias, float* __restrict__ Y) {
  int fo = blockIdx.x;
  int bc = blockIdx.y; int c = bc % CH; int b = bc / CH;
  int t = threadIdx.x;
  if (t >= T_) return;
  const float* wr = W + fo * F_;
  const float* wi = W + F_ * F_ + fo * F_;
  const float* xr = X + ((b * 2 + 0) * CH + c) * FT + t;
  const float* xi = X + ((b * 2 + 1) * CH + c) * FT + t;
  float ar = 0.f, ai = 0.f;
  for (int fi = 0; fi < F_; ++fi) {
    float wrv = wr[fi], wiv = wi[fi];
    float xrv = xr[fi * T_], xiv = xi[fi * T_];
    ar += wrv * xrv - wiv * xiv;
    ai += wrv * xiv + wiv * xrv;
  }
  float br = bias[fo], bi = bias[F_ + fo];
  Y[((b * 2 + 0) * CH + c) * FT + fo * T_ + t] = ar + br - bi;
  Y[((b * 2 + 1) * CH + c) * FT + fo * T_ + t] = ai + br + bi;
}

// ======== repack bodies (A-fragment order, hi/lo bf16 split) ========
template<int CIN, int K>
DEV void repack_real_body(const float* __restrict__ W, short* __restrict__ wpk, int i) {
  constexpr int CC = (CIN >= 32) ? (CIN / 32) : 1;
  constexpr int NSTEP = (CIN * K + 31) / 32;
  int total = 2 * NSTEP * 4 * 64 * 8;
  if (i >= total) return;
  int j = i & 7;
  int lane = (i >> 3) & 63;
  int mt = (i >> 9) & 3;
  int s = (i >> 11) % NSTEP;
  int split = i / (NSTEP * 2048);
  int q = lane >> 4;
  int m = mt * 16 + (lane & 15);
  int tap = s / CC;
  int c = (s % CC) * 32 + q * 8 + j;
  float w = 0.f;
  if (c < CIN && tap < K) w = W[(m * CIN + c) * K + tap];
  short hi = f2bf(w);
  wpk[i] = split ? f2bf(w - bf2f(hi)) : hi;
}

template<int CIN2, int COUT2, int K>
DEV void repack_cplx_body(const float* __restrict__ W, short* __restrict__ wpk, int i) {
  constexpr int CIN = CIN2 / 2, COUT = COUT2 / 2;
  constexpr int NSTEP = CIN2 * K / 32;
  constexpr int MT = (COUT2 + 15) / 16;
  int total = 2 * NSTEP * MT * 64 * 8;
  if (i >= total) return;
  int j = i & 7;
  int lane = (i >> 3) & 63;
  int idx = i >> 9;
  int mt = idx % MT; idx /= MT;
  int s = idx % NSTEP;
  int split = idx / NSTEP;
  int q = lane >> 4;
  int m = mt * 16 + (lane & 15);
  int tap, pi, ci;
  if constexpr (CIN2 == 128) {
    tap = 0;
    int cs = s * 32 + q * 8 + j;       // staged k index
    int half = cs / 64, r = cs % 64;
    ci = half * 32 + r / 2;
    pi = r & 1;
  } else {
    tap = s * 2 + (q >> 1);
    int cs = (q & 1) * 8 + j;
    pi = cs / CIN;
    ci = cs % CIN;
  }
  float w = 0.f;
  if (m < COUT2) {
    int po = m / COUT, ho = m % COUT;
    float wr = W[((0 * COUT + ho) * CIN + ci) * K + tap];
    float wi = W[((1 * COUT + ho) * CIN + ci) * K + tap];
    w = (po == pi) ? wr : (po == 0 ? -wi : wi);
  }
  short hi = f2bf(w);
  wpk[i] = split ? f2bf(w - bf2f(hi)) : hi;
}

__global__ __launch_bounds__(256) void k_repack_all(
    const float* c1r_w, const float* c1i_w, const float* c2r_w, const float* c2i_w,
    const float* c3r_w, const float* c3i_w, const float* c4r_w, const float* c4i_w,
    const float* c1_w, const float* c2_w, const float* c3_w, const float* c4_w,
    const float* f1_w, const float* f2_w,
    short* o0, short* o1, short* o2, short* o3, short* o4, short* o5, short* o6,
    short* o7, short* o8, short* o9, short* o10, short* o11, short* o12, short* o13) {
  int i = blockIdx.x * 256 + threadIdx.x;
  switch (blockIdx.y) {
    case 0:  repack_real_body<C_IN, 1>(c1r_w, o0, i); break;
    case 1:  repack_real_body<H_,   1>(c1i_w, o1, i); break;
    case 2:  repack_real_body<H_,   8>(c2r_w, o2, i); break;
    case 3:  repack_real_body<H_,   8>(c2i_w, o3, i); break;
    case 4:  repack_real_body<C_IN, 1>(c3r_w, o4, i); break;
    case 5:  repack_real_body<H_,   1>(c3i_w, o5, i); break;
    case 6:  repack_real_body<H_,   8>(c4r_w, o6, i); break;
    case 7:  repack_real_body<H_,   8>(c4i_w, o7, i); break;
    case 8:  repack_cplx_body<128, 128, 1>(c1_w, o8, i); break;
    case 9:  repack_cplx_body<16,  128, 8>(c2_w, o9, i); break;
    case 10: repack_cplx_body<128, 128, 1>(c3_w, o10, i); break;
    case 11: repack_cplx_body<16,  128, 8>(c4_w, o11, i); break;
    case 12: repack_cplx_body<128, 16,  1>(f1_w, o12, i); break;
    case 13: repack_cplx_body<128, 2,   1>(f2_w, o13, i); break;
  }
}

// ======== MFMA real conv, branch-merged: blockIdx.y = br*(B*2) + (b*2+p) ====
// PRO: 0 = none, 1 = lrelu on p==0 input, 2 = cLog (reads both parts),
//      3 = packed u32 hi/lo input (producer already applied activation)
// EPI: 0 = f32 + bias, 1 = packed u32 + bias + lrelu(p0), 2 = packed u32 + bias
template<int CIN, int K, int PRO, int EPI>
__global__ __launch_bounds__(256) void k_conv_mfma(
    const float* __restrict__ Xa, const float* __restrict__ Xb,
    const short* __restrict__ wpka, const short* __restrict__ wpkb,
    const float* __restrict__ biasa, const float* __restrict__ biasb,
    float* __restrict__ Ya, float* __restrict__ Yb) {
  constexpr int CC = (CIN >= 32) ? (CIN / 32) : 1;
  constexpr int NSTEP = (CIN * K + 31) / 32;
  constexpr int PITCH = 72;
  constexpr int ROWS = TW + (K - 1);
  __shared__ short xs_hi[ROWS * PITCH];
  __shared__ short xs_lo[ROWS * PITCH];
  int f = blockIdx.x;
  int y = blockIdx.y;
  int brsel = (y >= B_ * 2);
  int bp = y - brsel * (B_ * 2);
  int p = bp & 1; int b = bp >> 1;
  const float* X = brsel ? Xb : Xa;
  const short* wpk = brsel ? wpkb : wpka;
  const float* bias = brsel ? biasb : biasa;
  float* Y = brsel ? Yb : Ya;
  int t0 = blockIdx.z * TW;
  int tid = threadIdx.x;

  // -------- targeted zero-fill: only halo rows + (for CIN<32) the c-pad band
  {
    int lo_inval = (K - 1) - t0;                 // rows rr < lo_inval have t < 0
    if (lo_inval < 0) lo_inval = 0;
    int hi_start = T_ - t0 + (K - 1);            // rows rr >= hi_start have t >= T_
    if (hi_start > ROWS) hi_start = ROWS;
    for (int i = tid; i < lo_inval * PITCH; i += 256) { xs_hi[i] = 0; xs_lo[i] = 0; }
    int nhi = (ROWS - hi_start) * PITCH;
    for (int i = tid; i < nhi; i += 256) {
      int o = hi_start * PITCH + i;
      xs_hi[o] = 0; xs_lo[o] = 0;
    }
    if (CIN < 32) {                              // B-fragments read c in [0,32)
      constexpr int BAND = 32 - ((CIN < 32) ? CIN : 32);
      for (int i = tid; i < ROWS * BAND; i += 256) {
        int rr = i / BAND, c = CIN + i % BAND;
        xs_hi[rr * PITCH + c] = 0; xs_lo[rr * PITCH + c] = 0;
      }
    }
  }
  __syncthreads();

  const float* Xr_ = X + (size_t)((b * 2 + 0) * CIN) * FT + f * T_;
  const float* Xi_ = X + (size_t)((b * 2 + 1) * CIN) * FT + f * T_;
  const float* Xp  = X + (size_t)((b * 2 + p) * CIN) * FT + f * T_;
  const unsigned* Xu = (const unsigned*)X + (size_t)((b * 2 + p) * CIN) * FT + f * T_;
  {
    constexpr int STEP_C = 256 / ROWS, STEP_R = 256 % ROWS;
    int c = tid / ROWS;
    int rr = tid - c * ROWS;
    while (c < CIN) {
      int t = t0 + rr - (K - 1);
      if (t >= 0 && t < T_) {
        short hi, lo;
        if (PRO == 3) {
          unsigned v = Xu[c * FT + t];
          hi = (short)(v >> 16);
          lo = (short)(v & 0xffffu);
        } else {
          float v;
          if (PRO == 2) {
            float re = snap_f(Xr_[c * FT + t]);
            float im = snap_f(Xi_[c * FT + t]);
            v = (p == 0) ? __logf(sqrtf(im * im + re * re + EPSV * EPSV) + 1.f)
                         : fast_atan(im / re);
          } else {
            v = Xp[c * FT + t];
            if (PRO == 1 && p == 0) v = lrelu_f(v);
          }
          hi = f2bf(v);
          lo = f2bf(v - bf2f(hi));
        }
        xs_hi[rr * PITCH + c] = hi;
        xs_lo[rr * PITCH + c] = lo;
      }
      rr += STEP_R; c += STEP_C;
      if (rr >= ROWS) { rr -= ROWS; c += 1; }
    }
  }
  __syncthreads();

  int lane = tid & 63;
  int wv = __builtin_amdgcn_readfirstlane(tid >> 6);
  int mh = wv >> 1;           // mt-half: mt in {mh*2, mh*2+1}
  int tc = wv & 1;            // t-chunk within block
  int q = lane >> 4;
  int n = lane & 15;
  int wbase = tc * 48;

  float4v acc[2][3];
  #pragma unroll
  for (int mt = 0; mt < 2; ++mt)
    #pragma unroll
    for (int nt = 0; nt < 3; ++nt) acc[mt][nt] = (float4v)(0.f);

  const short8* wp = (const short8*)wpk;
  #pragma unroll
  for (int s = 0; s < NSTEP; ++s) {
    int tap = s / CC;
    int c0 = (s % CC) * 32;
    short8 Ah[2], Al[2];
    #pragma unroll
    for (int mt = 0; mt < 2; ++mt) {
      int mtg = mh * 2 + mt;
      Ah[mt] = wp[((0 * NSTEP + s) * 4 + mtg) * 64 + lane];
      Al[mt] = wp[((1 * NSTEP + s) * 4 + mtg) * 64 + lane];
    }
    short8 Bh[3], Bl[3];
    #pragma unroll
    for (int nt = 0; nt < 3; ++nt) {
      int off = (wbase + nt * 16 + n + tap) * PITCH + c0 + q * 8;
      Bh[nt] = *(const short8*)&xs_hi[off];
      Bl[nt] = *(const short8*)&xs_lo[off];
    }
    #pragma unroll
    for (int mt = 0; mt < 2; ++mt) {
      #pragma unroll
      for (int nt = 0; nt < 3; ++nt) {
        acc[mt][nt] = __builtin_amdgcn_mfma_f32_16x16x32_bf16(Ah[mt], Bh[nt], acc[mt][nt], 0, 0, 0);
        acc[mt][nt] = __builtin_amdgcn_mfma_f32_16x16x32_bf16(Ah[mt], Bl[nt], acc[mt][nt], 0, 0, 0);
        acc[mt][nt] = __builtin_amdgcn_mfma_f32_16x16x32_bf16(Al[mt], Bh[nt], acc[mt][nt], 0, 0, 0);
      }
    }
  }

  float* Yp = Y + (size_t)((b * 2 + p) * H_) * FT + f * T_;
  unsigned* Yu = (unsigned*)Y + (size_t)((b * 2 + p) * H_) * FT + f * T_;
  #pragma unroll
  for (int nt = 0; nt < 3; ++nt) {
    int t = t0 + wbase + nt * 16 + n;
    if (t >= T_) continue;
    #pragma unroll
    for (int mt = 0; mt < 2; ++mt) {
      #pragma unroll
      for (int r = 0; r < 4; ++r) {
        int h = (mh * 2 + mt) * 16 + q * 4 + r;
        float v = acc[mt][nt][r] + bias[h];
        if (EPI == 0) {
          Yp[h * FT + t] = v;
        } else {
          if (EPI == 1 && p == 0) v = lrelu_f(v);
          Yu[h * FT + t] = pack_hl(v);
        }
      }
    }
  }
}

// ======== MFMA complex conv CIN2=128 K=1, branch-merged, PRO=1 cexp+trelu ====
template<int COUT2, int PRO>
__global__ __launch_bounds__(256) void k_cconv128(
    const float* __restrict__ X0a, const float* __restrict__ X1a,
    const float* __restrict__ X0b, const float* __restrict__ X1b,
    const short* __restrict__ wpka, const short* __restrict__ wpkb,
    const float* __restrict__ ata, const float* __restrict__ atb,
    const float* __restrict__ aba, const float* __restrict__ abb,
    const float* __restrict__ biasa, const float* __restrict__ biasb,
    float* __restrict__ Ya, float* __restrict__ Yb) {
  constexpr int MT = (COUT2 + 15) / 16;
  constexpr int MTW = (MT > 4) ? 4 : MT;
  constexpr int COUT = COUT2 / 2;
  constexpr int NSTEP = 4;
  constexpr int PITCH = 72;
  __shared__ short xs_hi[TW * PITCH];
  __shared__ short xs_lo[TW * PITCH];
  __shared__ float coef[6][64];
  int f = blockIdx.x;
  int y = blockIdx.y;
  int brsel = (y >= B_);
  int b = y - brsel * B_;
  const float* X0 = brsel ? X0b : X0a;
  const float* X1 = brsel ? X1b : X1a;
  const short* wpk = brsel ? wpkb : wpka;
  const float* at = brsel ? atb : ata;
  const float* ab = brsel ? abb : aba;
  const float* bias = brsel ? biasb : biasa;
  float* Y = brsel ? Yb : Ya;
  int t0 = blockIdx.z * TW;
  int tid = threadIdx.x;
  int lane = tid & 63;
  int wv = __builtin_amdgcn_readfirstlane(tid >> 6);
  int mh = wv >> 1;
  int tc = wv & 1;
  int q = lane >> 4;
  int n = lane & 15;
  int wbase = tc * 48;

  if (tid < 64) {
    int h = tid;
    coef[0][h] = at[(0 * H_ + h) * F_ + f];
    coef[1][h] = at[(1 * H_ + h) * F_ + f];
    coef[2][h] = at[(2 * H_ + h) * F_ + f];
    coef[3][h] = at[(3 * H_ + h) * F_ + f];
    coef[4][h] = ab[h * F_ + f];
    coef[5][h] = ab[(H_ + h) * F_ + f];
  }
  // targeted zero-fill: only rows with t >= T_ (tail of z=1 chunk)
  {
    int inval0 = T_ - t0;
    if (inval0 < 0) inval0 = 0;
    if (inval0 > TW) inval0 = TW;
    int nfill = (TW - inval0) * PITCH;
    for (int i = tid; i < nfill; i += 256) {
      int o = inval0 * PITCH + i;
      xs_hi[o] = 0; xs_lo[o] = 0;
    }
  }

  const float* b0r = X0 + (size_t)((b * 2 + 0) * H_) * FT + f * T_;
  const float* b0i = X0 + (size_t)((b * 2 + 1) * H_) * FT + f * T_;
  const float* b1r = X1 + (size_t)((b * 2 + 0) * H_) * FT + f * T_;
  const float* b1i = X1 + (size_t)((b * 2 + 1) * H_) * FT + f * T_;

  float4v acc[MTW][3];
  #pragma unroll
  for (int mt = 0; mt < MTW; ++mt)
    #pragma unroll
    for (int nt = 0; nt < 3; ++nt) acc[mt][nt] = (float4v)(0.f);

  const short8* wp = (const short8*)wpk;
  for (int half = 0; half < 2; ++half) {
    __syncthreads();
    for (int i = tid; i < 32 * TW; i += 256) {
      int hh = i / TW, tl = i % TW;
      int t = t0 + tl;
      if (t >= T_) continue;
      int h = half * 32 + hh;
      float xr = b0r[h * FT + t], xi = b0i[h * FT + t];
      float vr, vi;
      if (PRO == 1) {
        float er, ei;
        cexp_f(xr, xi, er, ei);
        vr = lrelu_f(er * coef[0][h] + ei * coef[1][h] + coef[4][h]);
        vi = lrelu_f(er * coef[2][h] + ei * coef[3][h] + coef[5][h]);
      } else {
        float yr = b1r[h * FT + t], yi = b1i[h * FT + t];
        float mr = xr * yr - xi * yi;
        float mi = xr * yi + xi * yr;
        vr = lrelu_f(mr * coef[0][h] + mi * coef[1][h] + coef[4][h]);
        vi = lrelu_f(mr * coef[2][h] + mi * coef[3][h] + coef[5][h]);
      }
      int cs0 = hh * 2, cs1 = hh * 2 + 1;
      short hr = f2bf(vr), hi2 = f2bf(vi);
      xs_hi[tl * PITCH + cs0] = hr;
      xs_lo[tl * PITCH + cs0] = f2bf(vr - bf2f(hr));
      xs_hi[tl * PITCH + cs1] = hi2;
      xs_lo[tl * PITCH + cs1] = f2bf(vi - bf2f(hi2));
    }
    __syncthreads();
    #pragma unroll
    for (int s2 = 0; s2 < 2; ++s2) {
      int s = half * 2 + s2;
      short8 Bh[3], Bl[3];
      #pragma unroll
      for (int nt = 0; nt < 3; ++nt) {
        int off = (wbase + nt * 16 + n) * PITCH + s2 * 32 + q * 8;
        Bh[nt] = *(const short8*)&xs_hi[off];
        Bl[nt] = *(const short8*)&xs_lo[off];
      }
      #pragma unroll
      for (int mt = 0; mt < MTW; ++mt) {
        int mtg = mh * 4 + mt;
        if (mtg >= MT) continue;
        short8 Ah = wp[((0 * NSTEP + s) * MT + mtg) * 64 + lane];
        short8 Al = wp[((1 * NSTEP + s) * MT + mtg) * 64 + lane];
        #pragma unroll
        for (int nt = 0; nt < 3; ++nt) {
          acc[mt][nt] = __builtin_amdgcn_mfma_f32_16x16x32_bf16(Ah, Bh[nt], acc[mt][nt], 0, 0, 0);
          acc[mt][nt] = __builtin_amdgcn_mfma_f32_16x16x32_bf16(Ah, Bl[nt], acc[mt][nt], 0, 0, 0);
          acc[mt][nt] = __builtin_amdgcn_mfma_f32_16x16x32_bf16(Al, Bh[nt], acc[mt][nt], 0, 0, 0);
        }
      }
    }
  }

  float* Yp = Y + (size_t)b * COUT2 * FT + f * T_;
  #pragma unroll
  for (int nt = 0; nt < 3; ++nt) {
    int t = t0 + wbase + nt * 16 + n;
    if (t >= T_) continue;
    #pragma unroll
    for (int mt = 0; mt < MTW; ++mt) {
      int mtg = mh * 4 + mt;
      if (mtg >= MT) continue;
      #pragma unroll
      for (int r = 0; r < 4; ++r) {
        int o2 = mtg * 16 + q * 4 + r;
        if (o2 >= COUT2) continue;
        int po = o2 / COUT, ho = o2 % COUT;
        float br2 = bias[ho], bi2 = bias[COUT + ho];
        float badd = (po == 0) ? br2 - bi2 : br2 + bi2;
        Yp[o2 * FT + t] = acc[mt][nt][r] + badd;
      }
    }
  }
}

// ======== MFMA complex conv, CIN2=16, K=8 (real-ified), branch-merged ========
__global__ __launch_bounds__(256) void k_cconv16(
    const float* __restrict__ Xa, const float* __restrict__ Xb,
    const short* __restrict__ wpka, const short* __restrict__ wpkb,
    const float* __restrict__ biasa, const float* __restrict__ biasb,
    float* __restrict__ Ya, float* __restrict__ Yb) {
  constexpr int MT = 8, NSTEP = 4, PITCH = 24, ROWS = TW + 7, COUT = 64, COUT2 = 128;
  __shared__ short xs_hi[ROWS * PITCH];
  __shared__ short xs_lo[ROWS * PITCH];
  int f = blockIdx.x;
  int y = blockIdx.y;
  int brsel = (y >= B_);
  int b = y - brsel * B_;
  const float* X = brsel ? Xb : Xa;
  const short* wpk = brsel ? wpkb : wpka;
  const float* bias = brsel ? biasb : biasa;
  float* Y = brsel ? Yb : Ya;
  int t0 = blockIdx.z * TW;
  int tid = threadIdx.x;

  // targeted zero-fill: only halo rows (K=8, c band unused: reads c<16=CIN)
  {
    int lo_inval = 7 - t0;
    if (lo_inval < 0) lo_inval = 0;
    int hi_start = T_ - t0 + 7;
    if (hi_start > ROWS) hi_start = ROWS;
    for (int i = tid; i < lo_inval * PITCH; i += 256) { xs_hi[i] = 0; xs_lo[i] = 0; }
    int nhi = (ROWS - hi_start) * PITCH;
    for (int i = tid; i < nhi; i += 256) {
      int o = hi_start * PITCH + i;
      xs_hi[o] = 0; xs_lo[o] = 0;
    }
  }
  __syncthreads();

  const float* Xp = X + (size_t)b * 16 * FT + f * T_;
  for (int i = tid; i < 16 * ROWS; i += 256) {
    int c = i / ROWS, rr = i % ROWS;
    int t = t0 + rr - 7;
    if (t < 0 || t >= T_) continue;
    float v = Xp[c * FT + t];
    short hi = f2bf(v);
    short lo = f2bf(v - bf2f(hi));
    xs_hi[rr * PITCH + c] = hi;
    xs_lo[rr * PITCH + c] = lo;
  }
  __syncthreads();

  int lane = tid & 63;
  int wv = __builtin_amdgcn_readfirstlane(tid >> 6);
  int mh = wv >> 1;
  int tc = wv & 1;
  int q = lane >> 4;
  int n = lane & 15;
  int wbase = tc * 48;

  float4v acc[4][3];
  #pragma unroll
  for (int mt = 0; mt < 4; ++mt)
    #pragma unroll
    for (int nt = 0; nt < 3; ++nt) acc[mt][nt] = (float4v)(0.f);

  const short8* wp = (const short8*)wpk;
  #pragma unroll
  for (int s = 0; s < NSTEP; ++s) {
    int tap = s * 2 + (q >> 1);
    int coff = (q & 1) * 8;
    short8 Bh[3], Bl[3];
    #pragma unroll
    for (int nt = 0; nt < 3; ++nt) {
      int off = (wbase + nt * 16 + n + tap) * PITCH + coff;
      Bh[nt] = *(const short8*)&xs_hi[off];
      Bl[nt] = *(const short8*)&xs_lo[off];
    }
    #pragma unroll
    for (int mt = 0; mt < 4; ++mt) {
      int mtg = mh * 4 + mt;
      short8 Ah = wp[((0 * NSTEP + s) * MT + mtg) * 64 + lane];
      short8 Al = wp[((1 * NSTEP + s) * MT + mtg) * 64 + lane];
      #pragma unroll
      for (int nt = 0; nt < 3; ++nt) {
        acc[mt][nt] = __builtin_amdgcn_mfma_f32_16x16x32_bf16(Ah, Bh[nt], acc[mt][nt], 0, 0, 0);
        acc[mt][nt] = __builtin_amdgcn_mfma_f32_16x16x32_bf16(Ah, Bl[nt], acc[mt][nt], 0, 0, 0);
        acc[mt][nt] = __builtin_amdgcn_mfma_f32_16x16x32_bf16(Al, Bh[nt], acc[mt][nt], 0, 0, 0);
      }
    }
  }

  float* Yp = Y + (size_t)b * COUT2 * FT + f * T_;
  #pragma unroll
  for (int nt = 0; nt < 3; ++nt) {
    int t = t0 + wbase + nt * 16 + n;
    if (t >= T_) continue;
    #pragma unroll
    for (int mt = 0; mt < 4; ++mt) {
      #pragma unroll
      for (int r = 0; r < 4; ++r) {
        int o2 = (mh * 4 + mt) * 16 + q * 4 + r;
        int po = o2 / COUT, ho = o2 % COUT;
        float br2 = bias[ho], bi2 = bias[COUT + ho];
        float badd = (po == 0) ? br2 - bi2 : br2 + bi2;
        Yp[o2 * FT + t] = acc[mt][nt][r] + badd;
      }
    }
  }
}

// ---------------- cExp from packed u32 hi/lo input (branch-merged) -----------
__global__ void k_cexp_pk(const unsigned* __restrict__ Xa, const unsigned* __restrict__ Xb,
                          float* __restrict__ Ya, float* __restrict__ Yb) {
  int i = blockIdx.x * blockDim.x + threadIdx.x;
  if (i >= 2 * B_ * H_ * FT) return;
  int brsel = (i >= B_ * H_ * FT);
  int j = i - brsel * (B_ * H_ * FT);
  const unsigned* X = brsel ? Xb : Xa;
  float* Y = brsel ? Yb : Ya;
  int b = j / (H_ * FT);
  int r = j % (H_ * FT);
  size_t i0 = (size_t)(b * 2) * H_ * FT + r;
  size_t i1 = i0 + (size_t)H_ * FT;
  unsigned v0 = X[i0], v1 = X[i1];
  float tr = unpack_hl(v0);
  float ti = unpack_hl(v1);
  float er, ei;
  cexp_f(tr, ti, er, ei);
  Y[i0] = er;
  Y[i1] = ei;
}

__global__ void k_td1(const float* __restrict__ ts, const float* __restrict__ t8,
                      float* __restrict__ td1) {
  int i = blockIdx.x * blockDim.x + threadIdx.x;
  if (i >= B_ * 2 * FT) return;
  int bp = i / FT; int r = i % FT;
  const float* a = ts + bp * C_IN * FT + r;
  const float* c2 = t8 + bp * C_IN * FT + r;
  float acc = 0.f;
  #pragma unroll
  for (int c = 0; c < C_IN; ++c) acc += a[c * FT] - c2[c * FT];
  td1[i] = acc * (1.f / C_IN);
}

// ------------- fuse: cconv(concat) -> tgate -> blend -------------
__global__ void k_fuse(const float* __restrict__ tl1, const float* __restrict__ tl2,
                       const float* __restrict__ td1, const float* __restrict__ td2,
                       const float* __restrict__ cw, const float* __restrict__ cwb,
                       const float* __restrict__ fgt, const float* __restrict__ fgb,
                       float* __restrict__ td) {
  int i = blockIdx.x * blockDim.x + threadIdx.x;
  if (i >= B_ * FT) return;
  int b = i / FT; int r = i % FT; int f = r / T_;
  const float* x1r = tl1 + (b * 2) * H_ * FT + r;
  const float* x1i = x1r + H_ * FT;
  const float* x2r = tl2 + (b * 2) * H_ * FT + r;
  const float* x2i = x2r + H_ * FT;
  float fr = 0.f, fi = 0.f;
  for (int c = 0; c < H_; ++c) {
    float w1r = cw[c], w2r = cw[H_ + c], w1i = cw[2 * H_ + c], w2i = cw[3 * H_ + c];
    float a1r = x1r[c * FT], a1i = x1i[c * FT];
    float a2r = x2r[c * FT], a2i = x2i[c * FT];
    fr += w1r * a1r - w1i * a1i + w2r * a2r - w2i * a2i;
    fi += w1r * a1i + w1i * a1r + w2r * a2i + w2i * a2r;
  }
  fr += cwb[0] - cwb[1];
  fi += cwb[0] + cwb[1];
  float t00 = fgt[f], t01 = fgt[F_ + f], t10 = fgt[2 * F_ + f], t11 = fgt[3 * F_ + f];
  float gr = sigmoid_f(fr * t00 + fi * t01 + fgb[f]);
  float gi = sigmoid_f(fr * t10 + fi * t11 + fgb[F_ + f]);
  float gg = gr * gi + (1.f - gr) * (1.f - gi);
  int i0 = (b * 2) * FT + r, i1 = i0 + FT;
  td[i0] = td1[i0] * gg + td2[i0] * (1.f - gg);
  td[i1] = td1[i1] * gg + td2[i1] * (1.f - gg);
}

// ------------- iSTFT frames: folded rotation inverse DFT -------------
__global__ __launch_bounds__(320) void k_iframes(const float* __restrict__ sp,
                                                 float* __restrict__ frames) {
  __shared__ float Xr[F_], Xi[F_];
  int blk = blockIdx.x;
  int t = blk % T_;
  int b = blk / T_;
  int tid = threadIdx.x;
  for (int i = tid; i < F_; i += 320) {
    Xr[i] = sp[(b * 2 + 0) * FT + i * T_ + t];
    Xi[i] = sp[(b * 2 + 1) * FT + i * T_ + t];
  }
  __syncthreads();
  int n = tid;
  if (n <= 256) {
    float sd, cd;
    sincosf((PI2 / NFFT) * n, &sd, &cd);
    float cs = cd, sn = sd;
    float ac = 0.f, as = 0.f;
    for (int f = 1; f < 256; ++f) {
      ac += Xr[f] * cs;
      as += Xi[f] * sn;
      float t2 = cs * cd - sn * sd;
      sn = sn * cd + cs * sd;
      cs = t2;
    }
    float base = Xr[0] + Xr[256] * (1.f - 2.f * (n & 1));
    float win = 0.5f - 0.5f * cd;
    float scale = win * (1.f / NFFT);
    float* fr = frames + (size_t)(b * T_ + t) * NFFT;
    fr[n] = (base + 2.f * ac - 2.f * as) * scale;
    if (n >= 1 && n <= 255)
      fr[NFFT - n] = (base + 2.f * ac + 2.f * as) * scale;
  }
}

// ------------- overlap-add + wsum normalize + center-crop -------------
__global__ void k_ola(const float* __restrict__ frames, float* __restrict__ out) {
  int i = blockIdx.x * blockDim.x + threadIdx.x;
  if (i >= B_ * LEN) return;
  int b = i / LEN; int j = i % LEN;
  int p = j + PADL;
  int t0 = p / HOP; int n0 = p - t0 * HOP;
  float acc = 0.f, wsum = 0.f;
  if (t0 < T_) {
    acc += frames[(b * T_ + t0) * NFFT + n0];
    float w = 0.5f - 0.5f * __cosf((PI2 / NFFT) * n0);
    wsum += w * w;
  }
  int t1 = t0 - 1, n1 = n0 + HOP;
  if (t1 >= 0 && t1 < T_) {
    acc += frames[(b * T_ + t1) * NFFT + n1];
    float w = 0.5f - 0.5f * __cosf((PI2 / NFFT) * n1);
    wsum += w * w;
  }
  out[i] = acc / fmaxf(wsum, 1e-11f);
}

extern "C" void kernel_launch(void* const* d_in, const int* in_sizes, int n_in,
                              void* d_out, int out_size, void* d_ws, size_t ws_size,
                              hipStream_t stream) {
  const float* mix   = (const float*)d_in[0];
  const float* fs_w  = (const float*)d_in[1];
  const float* fs_b  = (const float*)d_in[2];
  const float* fr_w  = (const float*)d_in[3];
  const float* fr_b  = (const float*)d_in[4];
  const float* c1r_w = (const float*)d_in[5];
  const float* c1r_b = (const float*)d_in[6];
  const float* c1i_w = (const float*)d_in[7];
  const float* c1i_b = (const float*)d_in[8];
  const float* c1_w  = (const float*)d_in[9];
  const float* c1_b  = (const float*)d_in[10];
  const float* c2r_w = (const float*)d_in[11];
  const float* c2r_b = (const float*)d_in[12];
  const float* c2i_w = (const float*)d_in[13];
  const float* c2i_b = (const float*)d_in[14];
  const float* c2_w  = (const float*)d_in[15];
  const float* c2_b  = (const float*)d_in[16];
  const float* a1_t  = (const float*)d_in[17];
  const float* a1_b  = (const float*)d_in[18];
  const float* a2_t  = (const float*)d_in[19];
  const float* a2_b  = (const float*)d_in[20];
  const float* c3r_w = (const float*)d_in[21];
  const float* c3r_b = (const float*)d_in[22];
  const float* c3i_w = (const float*)d_in[23];
  const float* c3i_b = (const float*)d_in[24];
  const float* c3_w  = (const float*)d_in[25];
  const float* c3_b  = (const float*)d_in[26];
  const float* c4r_w = (const float*)d_in[27];
  const float* c4r_b = (const float*)d_in[28];
  const float* c4i_w = (const float*)d_in[29];
  const float* c4i_b = (const float*)d_in[30];
  const float* c4_w  = (const float*)d_in[31];
  const float* c4_b  = (const float*)d_in[32];
  const float* a3_t  = (const float*)d_in[33];
  const float* a3_b  = (const float*)d_in[34];
  const float* a4_t  = (const float*)d_in[35];
  const float* a4_b  = (const float*)d_in[36];
  const float* f1_w  = (const float*)d_in[37];
  const float* f1_b  = (const float*)d_in[38];
  const float* f2_w  = (const float*)d_in[39];
  const float* f2_b  = (const float*)d_in[40];
  const float* cw_w  = (const float*)d_in[41];
  const float* cw_b  = (const float*)d_in[42];
  const float* fg_t  = (const float*)d_in[43];
  const float* fg_b  = (const float*)d_in[44];

  const size_t S8 = (size_t)B_ * 2 * C_IN * FT;
  const size_t SH = (size_t)B_ * 2 * H_ * FT;
  const size_t S1 = (size_t)B_ * 2 * FT;
  float* ws  = (float*)d_ws;
  float* ts0 = ws;
  float* ts  = ts0 + S8;
  float* A1  = ts + S8;
  float* A2  = A1 + SH;
  float* Bb  = A2 + SH;
  float* Cc  = Bb + SH;
  float* td1 = Cc + SH;
  float* td2 = td1 + S1;
  float* tdf = td2 + S1;
  float* tdr = tdf + S1;
  float* s8  = ts0;
  float* frames = ts0;

  short* wtail = (short*)(tdr + S1);
  constexpr int SZ_C8K1   = 2 * 1  * 4 * 64 * 8;
  constexpr int SZ_C64K1  = 2 * 2  * 4 * 64 * 8;
  constexpr int SZ_C64K8  = 2 * 16 * 4 * 64 * 8;
  constexpr int SZ_CC128  = 2 * 4  * 8 * 64 * 8;
  constexpr int SZ_CF     = 2 * 4  * 1 * 64 * 8;
  constexpr int SZ_SM     = 2 * 16 * 33 * 64 * 8;   // stft+mix fused matrix
  short* w_c1r = wtail;
  short* w_c1i = w_c1r + SZ_C8K1;
  short* w_c2r = w_c1i + SZ_C64K1;
  short* w_c2i = w_c2r + SZ_C64K8;
  short* w_c3r = w_c2i + SZ_C64K8;
  short* w_c3i = w_c3r + SZ_C8K1;
  short* w_c4r = w_c3i + SZ_C64K1;
  short* w_c4i = w_c4r + SZ_C64K8;
  short* w_cc1 = w_c4i + SZ_C64K8;
  short* w_cc2 = w_cc1 + SZ_CC128;
  short* w_cc3 = w_cc2 + SZ_CC128;
  short* w_cc4 = w_cc3 + SZ_CC128;
  short* w_cf1 = w_cc4 + SZ_CC128;
  short* w_cf2 = w_cf1 + SZ_CF;
  short* w_sm  = w_cf2 + SZ_CF;
  short* mhi   = w_sm + SZ_SM;
  short* mlo   = mhi + (size_t)B_ * C_IN * LEN;

  const int nH = B_ * H_ * FT;
  const int nP = B_ * FT;
  const dim3 mrgrid(F_, 2 * B_ * 2, 2);  // merged real convs: (f, br*(b*2+p), t-half)
  const dim3 mcgrid(F_, 2 * B_, 2);      // merged complex convs: (f, br*b, t-half)
  const dim3 cgrid(F_, B_, 2);           // single-branch complex convs

  k_repack_all<<<dim3(256, 14), 256, 0, stream>>>(
      c1r_w, c1i_w, c2r_w, c2i_w, c3r_w, c3i_w, c4r_w, c4i_w,
      c1_w, c2_w, c3_w, c4_w, f1_w, f2_w,
      w_c1r, w_c1i, w_c2r, w_c2i, w_c3r, w_c3i, w_c4r, w_c4i,
      w_cc1, w_cc2, w_cc3, w_cc4, w_cf1, w_cf2);

  // fused STFT + frequency mixing (M = fs_w x win*DFT, then MFMA GEMM)
  k_mixsplit<<<(B_ * C_IN * LEN / 4 + 255) / 256, 256, 0, stream>>>(mix, mhi, mlo);
  k_mixdft<<<dim3(528, 2), 256, 0, stream>>>(fs_w, w_sm);
  k_stftmix<<<dim3(9, 16, 4), 256, 0, stream>>>(mhi, mlo, w_sm, fs_b, ts);

  // ---- both branches, co-scheduled layer by layer ----
  k_conv_mfma<C_IN, 1, 2, 1><<<mrgrid, 256, 0, stream>>>(
      ts, ts, w_c1r, w_c3r, c1r_b, c3r_b, A1, A2);                 // cLog+c{1,3}r
  k_conv_mfma<H_, 1, 3, 0><<<mrgrid, 256, 0, stream>>>(
      A1, A2, w_c1i, w_c3i, c1i_b, c3i_b, Bb, Cc);                 // +c{1,3}i
  k_cconv128<128, 1><<<mcgrid, 256, 0, stream>>>(
      Bb, Bb, Cc, Cc, w_cc1, w_cc3, a1_t, a3_t, a1_b, a3_b,
      c1_b, c3_b, A1, A2);                                          // cexp+trelu+c{1,3}
  k_conv_mfma<H_, 8, 2, 1><<<mrgrid, 256, 0, stream>>>(
      A1, A2, w_c2r, w_c4r, c2r_b, c4r_b, Bb, Cc);                 // cLog+c{2,4}r
  k_conv_mfma<H_, 8, 3, 2><<<mrgrid, 256, 0, stream>>>(
      Bb, Cc, w_c2i, w_c4i, c2i_b, c4i_b, A1, A2);                 // +c{2,4}i (packed)
  k_cexp_pk<<<(2 * nH + 255) / 256, 256, 0, stream>>>(
      (const unsigned*)A1, (const unsigned*)A2, Bb, Cc);           // Bb=tl1, Cc=tl2
  k_cconv16<<<mcgrid, 256, 0, stream>>>(
      ts, ts, w_cc2, w_cc4, c2_b, c4_b, A1, A2);                   // tc1->A1, tc2->A2
  k_cconv128<16, 2><<<cgrid, 256, 0, stream>>>(
      Bb, A1, Bb, A1, w_cf1, w_cf1, a2_t, a2_t, a2_b, a2_b,
      f1_b, f1_b, s8, s8);                                          // cmul+trelu+f1
  k_td1<<<(B_ * 2 * FT + 255) / 256, 256, 0, stream>>>(ts, s8, td1);
  k_cconv128<2, 2><<<cgrid, 256, 0, stream>>>(
      Cc, A2, Cc, A2, w_cf2, w_cf2, a4_t, a4_t, a4_b, a4_b,
      f2_b, f2_b, td2, td2);                                        // cmul+trelu+f2

  // ---- fuse + unmix + iSTFT ----
  k_fuse<<<(nP + 255) / 256, 256, 0, stream>>>(Bb, Cc, td1, td2, cw_w, cw_b, fg_t, fg_b, tdf);
  k_fmix<1><<<dim3(F_, B_), 192, 0, stream>>>(tdf, fr_w, fr_b, tdr);
  k_iframes<<<B_ * T_, 320, 0, stream>>>(tdr, frames);
  k_ola<<<(B_ * LEN + 255) / 256, 256, 0, stream>>>(frames, (float*)d_out);
}

// Round 15
// 747.738 us; speedup vs baseline: 1.0687x; 1.0687x over previous
//
#include <hip/hip_runtime.h>
#include <math.h>

#define DEV __device__ __forceinline__

constexpr int B_   = 2;
constexpr int C_IN = 8;
constexpr int H_   = 64;
constexpr int F_   = 257;
constexpr int T_   = 188;
constexpr int TW   = 96;    // t-columns per block (T split in 2)
constexpr int NFFT = 512;
constexpr int HOP  = 256;
constexpr int LEN  = 48000;
constexpr int PADL = 256;
constexpr int FT   = F_ * T_;
constexpr float EPSV  = 1e-4f;
constexpr float SLOPEV = 0.01f;
constexpr float PI2 = 6.283185307179586f;

typedef __attribute__((ext_vector_type(8))) short short8;
typedef __attribute__((ext_vector_type(4))) short short4v;
typedef __attribute__((ext_vector_type(4))) float float4v;

DEV float lrelu_f(float x) { return x > 0.f ? x : SLOPEV * x; }
DEV float snap_f(float x) {
  if (x >= 0.f && x < EPSV) return EPSV;
  if (x < 0.f && x > -EPSV) return -EPSV;
  return x;
}
DEV float fast_atan(float z) {
  float az = fabsf(z);
  float u = az > 1.f ? __builtin_amdgcn_rcpf(az) : az;
  float u2 = u * u;
  float p = -0.01172120f;
  p = p * u2 + 0.05265332f;
  p = p * u2 - 0.11643287f;
  p = p * u2 + 0.19354346f;
  p = p * u2 - 0.33262347f;
  p = p * u2 + 0.99997726f;
  float r = p * u;
  if (az > 1.f) r = 1.5707963267948966f - r;
  return z < 0.f ? -r : r;
}
DEV float modexp_f(float x) {
  const float em = 148.4131591025766f; // e^5
  return x > 5.f ? (x - 5.f) * em + em : __expf(x);
}
DEV void cexp_f(float tr, float ti, float& er, float& ei) {
  float e = modexp_f(tr) - 1.f;
  float a = ti - 1.f;
  er = e * __cosf(a); ei = e * __sinf(a);
}
DEV float sigmoid_f(float x) { return 1.f / (1.f + __expf(-x)); }

DEV short f2bf(float x) {   // RNE float->bf16
  unsigned u = __float_as_uint(x);
  unsigned r = (u + 0x7fffu + ((u >> 16) & 1u)) >> 16;
  return (short)r;
}
DEV float bf2f(short h) {
  return __uint_as_float(((unsigned)(unsigned short)h) << 16);
}
DEV unsigned pack_hl(float v) {
  short hi = f2bf(v);
  short lo = f2bf(v - bf2f(hi));
  return ((unsigned)(unsigned short)hi << 16) | (unsigned)(unsigned short)lo;
}
DEV float unpack_hl(unsigned v) {
  return bf2f((short)(v >> 16)) + bf2f((short)(v & 0xffffu));
}

// ---------------- mix -> bf16 hi/lo pre-split (staging feed for k_stftmix) --
__global__ void k_mixsplit(const float* __restrict__ x, short* __restrict__ hi,
                           short* __restrict__ lo) {
  int i = blockIdx.x * 256 + threadIdx.x;
  if (i >= B_ * C_IN * LEN / 4) return;
  float4v v = *(const float4v*)(x + (size_t)i * 4);
  short4v h, l;
  #pragma unroll
  for (int j = 0; j < 4; ++j) {
    h[j] = f2bf(v[j]);
    l[j] = f2bf(v[j] - bf2f(h[j]));
  }
  *(short4v*)(hi + (size_t)i * 4) = h;
  *(short4v*)(lo + (size_t)i * 4) = l;
}

// -------- combined (fs_w x windowed-DFT) matrix -> A-fragments hi/lo --------
__global__ __launch_bounds__(256) void k_mixdft(const float* __restrict__ W,
                                                short* __restrict__ wpk) {
  constexpr int MT = 33;
  __shared__ float wr_s[F_], wi_s[F_];
  int m = blockIdx.x;                       // 0..527
  int k = blockIdx.y * 256 + threadIdx.x;   // 0..511
  int po = m >= F_;
  int fo = m - po * F_;
  if (m < 2 * F_) {
    for (int i = threadIdx.x; i < F_; i += 256) {
      wr_s[i] = W[fo * F_ + i];
      wi_s[i] = W[F_ * F_ + fo * F_ + i];
    }
  }
  __syncthreads();
  float val = 0.f;
  if (m < 2 * F_) {
    float sd, cd;
    sincosf((PI2 / NFFT) * k, &sd, &cd);    // step angle 2*pi*k/512
    float cs = 1.f, sn = 0.f;               // fi = 0
    float ar = 0.f, ai = 0.f;
    for (int fi = 0; fi < F_; ++fi) {
      float wrv = wr_s[fi], wiv = wi_s[fi];
      ar += wrv * cs + wiv * sn;
      ai += wiv * cs - wrv * sn;
      float t2 = cs * cd - sn * sd;
      sn = sn * cd + cs * sd;
      cs = t2;
    }
    float win = 0.5f - 0.5f * cd;           // hann(k) reuses cd = cos(2pi k/512)
    val = (po ? ai : ar) * win;
  }
  int mtg = m >> 4;
  int lane2 = ((k >> 3) & 3) * 16 + (m & 15);
  int s = k >> 5;
  int j = k & 7;
  short hi = f2bf(val);
  short lo = f2bf(val - bf2f(hi));
  wpk[(((0 * 16 + s) * MT + mtg) * 64 + lane2) * 8 + j] = hi;
  wpk[(((16 + s) * MT + mtg) * 64 + lane2) * 8 + j] = lo;
}

// ======== fused STFT + freq-mix: ts = M @ frames(mix), hi/lo bf16 MFMA ======
constexpr int TWS = 48;
__global__ __launch_bounds__(256) void k_stftmix(
    const short* __restrict__ mhi, const short* __restrict__ mlo,
    const short* __restrict__ wpk, const float* __restrict__ bias,
    float* __restrict__ Y) {
  constexpr int PITCH = 136;
  constexpr int MT = 33;
  __shared__ short xs_hi[TWS * PITCH];
  __shared__ short xs_lo[TWS * PITCH];
  int mg = blockIdx.x;
  int bc = blockIdx.y;
  int b = bc >> 3, c = bc & 7;
  int t0 = blockIdx.z * TWS;
  int tid = threadIdx.x;
  int lane = tid & 63;
  int wv = __builtin_amdgcn_readfirstlane(tid >> 6);
  int mtg = mg * 4 + wv;
  int q = lane >> 4;
  int n = lane & 15;

  const short* mh_ = mhi + (size_t)(b * C_IN + c) * LEN;
  const short* ml_ = mlo + (size_t)(b * C_IN + c) * LEN;

  float4v acc[3];
  #pragma unroll
  for (int nt = 0; nt < 3; ++nt) acc[nt] = (float4v)(0.f);

  const short8* wp = (const short8*)wpk;
  for (int round = 0; round < 4; ++round) {   // 128 k per round
    if (round) __syncthreads();
    for (int i = tid; i < TWS * 16; i += 256) {
      int tl = i >> 4, u = i & 15;
      int kk0 = u * 8;
      int t = t0 + tl;
      int g0 = t * HOP + round * 128 + kk0 - PADL;
      short8 h, l;
      if (t < T_ && g0 >= 0 && g0 + 7 < LEN) {
        h = *(const short8*)(mh_ + g0);
        l = *(const short8*)(ml_ + g0);
      } else {
        #pragma unroll
        for (int j = 0; j < 8; ++j) {
          short hv = 0, lv = 0;
          if (t < T_) {
            int g = g0 + j;
            if (g < 0) g = -g;
            if (g >= LEN) g = 2 * LEN - 2 - g;
            hv = mh_[g]; lv = ml_[g];
          }
          h[j] = hv; l[j] = lv;
        }
      }
      *(short8*)&xs_hi[tl * PITCH + kk0] = h;
      *(short8*)&xs_lo[tl * PITCH + kk0] = l;
    }
    __syncthreads();
    #pragma unroll
    for (int s2 = 0; s2 < 4; ++s2) {
      int s = round * 4 + s2;
      short8 Ah, Al;
      if (mtg < MT) {
        Ah = wp[((0 * 16 + s) * MT + mtg) * 64 + lane];
        Al = wp[((16 + s) * MT + mtg) * 64 + lane];
      }
      short8 Bh[3], Bl[3];
      #pragma unroll
      for (int nt = 0; nt < 3; ++nt) {
        int off = (nt * 16 + n) * PITCH + s2 * 32 + q * 8;
        Bh[nt] = *(const short8*)&xs_hi[off];
        Bl[nt] = *(const short8*)&xs_lo[off];
      }
      if (mtg < MT) {
        #pragma unroll
        for (int nt = 0; nt < 3; ++nt) {
          acc[nt] = __builtin_amdgcn_mfma_f32_16x16x32_bf16(Ah, Bh[nt], acc[nt], 0, 0, 0);
          acc[nt] = __builtin_amdgcn_mfma_f32_16x16x32_bf16(Ah, Bl[nt], acc[nt], 0, 0, 0);
          acc[nt] = __builtin_amdgcn_mfma_f32_16x16x32_bf16(Al, Bh[nt], acc[nt], 0, 0, 0);
        }
      }
    }
  }

  if (mtg < MT) {
    #pragma unroll
    for (int nt = 0; nt < 3; ++nt) {
      int t = t0 + nt * 16 + n;
      if (t >= T_) continue;
      #pragma unroll
      for (int r = 0; r < 4; ++r) {
        int m = mtg * 16 + q * 4 + r;
        if (m >= 2 * F_) continue;
        int po = m >= F_;
        int fo = m - po * F_;
        float badd = po ? bias[fo] + bias[F_ + fo] : bias[fo] - bias[F_ + fo];
        Y[((size_t)((b * 2 + po) * C_IN + c)) * FT + fo * T_ + t] = acc[nt][r] + badd;
      }
    }
  }
}

// ---------- frequency mixing: complex (F x F) matvec per (b,c,t) ----------
template<int CH>
__global__ void k_fmix(const float* __restrict__ X, const float* __restrict__ W,
                       const float* __restrict__ bias, float* __restrict__ Y) {
  int fo = blockIdx.x;
  int bc = blockIdx.y; int c = bc % CH; int b = bc / CH;
  int t = threadIdx.x;
  if (t >= T_) return;
  const float* wr = W + fo * F_;
  const float* wi = W + F_ * F_ + fo * F_;
  const float* xr = X + ((b * 2 + 0) * CH + c) * FT + t;
  const float* xi = X + ((b * 2 + 1) * CH + c) * FT + t;
  float ar = 0.f, ai = 0.f;
  for (int fi = 0; fi < F_; ++fi) {
    float wrv = wr[fi], wiv = wi[fi];
    float xrv = xr[fi * T_], xiv = xi[fi * T_];
    ar += wrv * xrv - wiv * xiv;
    ai += wrv * xiv + wiv * xrv;
  }
  float br = bias[fo], bi = bias[F_ + fo];
  Y[((b * 2 + 0) * CH + c) * FT + fo * T_ + t] = ar + br - bi;
  Y[((b * 2 + 1) * CH + c) * FT + fo * T_ + t] = ai + br + bi;
}

// ======== repack bodies (A-fragment order, hi/lo bf16 split) ========
template<int CIN, int K>
DEV void repack_real_body(const float* __restrict__ W, short* __restrict__ wpk, int i) {
  constexpr int CC = (CIN >= 32) ? (CIN / 32) : 1;
  constexpr int NSTEP = (CIN * K + 31) / 32;
  int total = 2 * NSTEP * 4 * 64 * 8;
  if (i >= total) return;
  int j = i & 7;
  int lane = (i >> 3) & 63;
  int mt = (i >> 9) & 3;
  int s = (i >> 11) % NSTEP;
  int split = i / (NSTEP * 2048);
  int q = lane >> 4;
  int m = mt * 16 + (lane & 15);
  int tap = s / CC;
  int c = (s % CC) * 32 + q * 8 + j;
  float w = 0.f;
  if (c < CIN && tap < K) w = W[(m * CIN + c) * K + tap];
  short hi = f2bf(w);
  wpk[i] = split ? f2bf(w - bf2f(hi)) : hi;
}

template<int CIN2, int COUT2, int K>
DEV void repack_cplx_body(const float* __restrict__ W, short* __restrict__ wpk, int i) {
  constexpr int CIN = CIN2 / 2, COUT = COUT2 / 2;
  constexpr int NSTEP = CIN2 * K / 32;
  constexpr int MT = (COUT2 + 15) / 16;
  int total = 2 * NSTEP * MT * 64 * 8;
  if (i >= total) return;
  int j = i & 7;
  int lane = (i >> 3) & 63;
  int idx = i >> 9;
  int mt = idx % MT; idx /= MT;
  int s = idx % NSTEP;
  int split = idx / NSTEP;
  int q = lane >> 4;
  int m = mt * 16 + (lane & 15);
  int tap, pi, ci;
  if constexpr (CIN2 == 128) {
    tap = 0;
    int cs = s * 32 + q * 8 + j;       // staged k index
    int half = cs / 64, r = cs % 64;
    ci = half * 32 + r / 2;
    pi = r & 1;
  } else {
    tap = s * 2 + (q >> 1);
    int cs = (q & 1) * 8 + j;
    pi = cs / CIN;
    ci = cs % CIN;
  }
  float w = 0.f;
  if (m < COUT2) {
    int po = m / COUT, ho = m % COUT;
    float wr = W[((0 * COUT + ho) * CIN + ci) * K + tap];
    float wi = W[((1 * COUT + ho) * CIN + ci) * K + tap];
    w = (po == pi) ? wr : (po == 0 ? -wi : wi);
  }
  short hi = f2bf(w);
  wpk[i] = split ? f2bf(w - bf2f(hi)) : hi;
}

__global__ __launch_bounds__(256) void k_repack_all(
    const float* c1r_w, const float* c1i_w, const float* c2r_w, const float* c2i_w,
    const float* c3r_w, const float* c3i_w, const float* c4r_w, const float* c4i_w,
    const float* c1_w, const float* c2_w, const float* c3_w, const float* c4_w,
    const float* f1_w, const float* f2_w,
    short* o0, short* o1, short* o2, short* o3, short* o4, short* o5, short* o6,
    short* o7, short* o8, short* o9, short* o10, short* o11, short* o12, short* o13) {
  int i = blockIdx.x * 256 + threadIdx.x;
  switch (blockIdx.y) {
    case 0:  repack_real_body<C_IN, 1>(c1r_w, o0, i); break;
    case 1:  repack_real_body<H_,   1>(c1i_w, o1, i); break;
    case 2:  repack_real_body<H_,   8>(c2r_w, o2, i); break;
    case 3:  repack_real_body<H_,   8>(c2i_w, o3, i); break;
    case 4:  repack_real_body<C_IN, 1>(c3r_w, o4, i); break;
    case 5:  repack_real_body<H_,   1>(c3i_w, o5, i); break;
    case 6:  repack_real_body<H_,   8>(c4r_w, o6, i); break;
    case 7:  repack_real_body<H_,   8>(c4i_w, o7, i); break;
    case 8:  repack_cplx_body<128, 128, 1>(c1_w, o8, i); break;
    case 9:  repack_cplx_body<16,  128, 8>(c2_w, o9, i); break;
    case 10: repack_cplx_body<128, 128, 1>(c3_w, o10, i); break;
    case 11: repack_cplx_body<16,  128, 8>(c4_w, o11, i); break;
    case 12: repack_cplx_body<128, 16,  1>(f1_w, o12, i); break;
    case 13: repack_cplx_body<128, 2,   1>(f2_w, o13, i); break;
  }
}

// ======== MFMA real conv, branch-merged: blockIdx.y = br*(B*2) + (b*2+p) ====
// PRO: 0 = none, 1 = lrelu on p==0 input, 2 = cLog (reads both parts),
//      3 = packed u32 hi/lo input (producer already applied activation)
// EPI: 0 = f32 + bias, 1 = packed u32 + bias + lrelu(p0), 2 = packed u32 + bias
template<int CIN, int K, int PRO, int EPI>
__global__ __launch_bounds__(256) void k_conv_mfma(
    const float* __restrict__ Xa, const float* __restrict__ Xb,
    const short* __restrict__ wpka, const short* __restrict__ wpkb,
    const float* __restrict__ biasa, const float* __restrict__ biasb,
    float* __restrict__ Ya, float* __restrict__ Yb) {
  constexpr int CC = (CIN >= 32) ? (CIN / 32) : 1;
  constexpr int NSTEP = (CIN * K + 31) / 32;
  constexpr int PITCH = 72;
  constexpr int ROWS = TW + (K - 1);
  __shared__ short xs_hi[ROWS * PITCH];
  __shared__ short xs_lo[ROWS * PITCH];
  int f = blockIdx.x;
  int y = blockIdx.y;
  int brsel = (y >= B_ * 2);
  int bp = y - brsel * (B_ * 2);
  int p = bp & 1; int b = bp >> 1;
  const float* X = brsel ? Xb : Xa;
  const short* wpk = brsel ? wpkb : wpka;
  const float* bias = brsel ? biasb : biasa;
  float* Y = brsel ? Yb : Ya;
  int t0 = blockIdx.z * TW;
  int tid = threadIdx.x;

  // -------- targeted zero-fill: only halo rows + (for CIN<32) the c-pad band
  {
    int lo_inval = (K - 1) - t0;                 // rows rr < lo_inval have t < 0
    if (lo_inval < 0) lo_inval = 0;
    int hi_start = T_ - t0 + (K - 1);            // rows rr >= hi_start have t >= T_
    if (hi_start > ROWS) hi_start = ROWS;
    for (int i = tid; i < lo_inval * PITCH; i += 256) { xs_hi[i] = 0; xs_lo[i] = 0; }
    int nhi = (ROWS - hi_start) * PITCH;
    for (int i = tid; i < nhi; i += 256) {
      int o = hi_start * PITCH + i;
      xs_hi[o] = 0; xs_lo[o] = 0;
    }
    if (CIN < 32) {                              // B-fragments read c in [0,32)
      constexpr int BAND = 32 - ((CIN < 32) ? CIN : 32);
      for (int i = tid; i < ROWS * BAND; i += 256) {
        int rr = i / BAND, c = CIN + i % BAND;
        xs_hi[rr * PITCH + c] = 0; xs_lo[rr * PITCH + c] = 0;
      }
    }
  }
  __syncthreads();

  const float* Xr_ = X + (size_t)((b * 2 + 0) * CIN) * FT + f * T_;
  const float* Xi_ = X + (size_t)((b * 2 + 1) * CIN) * FT + f * T_;
  const float* Xp  = X + (size_t)((b * 2 + p) * CIN) * FT + f * T_;
  const unsigned* Xu = (const unsigned*)X + (size_t)((b * 2 + p) * CIN) * FT + f * T_;
  {
    constexpr int STEP_C = 256 / ROWS, STEP_R = 256 % ROWS;
    int c = tid / ROWS;
    int rr = tid - c * ROWS;
    while (c < CIN) {
      int t = t0 + rr - (K - 1);
      if (t >= 0 && t < T_) {
        short hi, lo;
        if (PRO == 3) {
          unsigned v = Xu[c * FT + t];
          hi = (short)(v >> 16);
          lo = (short)(v & 0xffffu);
        } else {
          float v;
          if (PRO == 2) {
            float re = snap_f(Xr_[c * FT + t]);
            float im = snap_f(Xi_[c * FT + t]);
            v = (p == 0) ? __logf(sqrtf(im * im + re * re + EPSV * EPSV) + 1.f)
                         : fast_atan(im / re);
          } else {
            v = Xp[c * FT + t];
            if (PRO == 1 && p == 0) v = lrelu_f(v);
          }
          hi = f2bf(v);
          lo = f2bf(v - bf2f(hi));
        }
        xs_hi[rr * PITCH + c] = hi;
        xs_lo[rr * PITCH + c] = lo;
      }
      rr += STEP_R; c += STEP_C;
      if (rr >= ROWS) { rr -= ROWS; c += 1; }
    }
  }
  __syncthreads();

  int lane = tid & 63;
  int wv = __builtin_amdgcn_readfirstlane(tid >> 6);
  int mh = wv >> 1;           // mt-half: mt in {mh*2, mh*2+1}
  int tc = wv & 1;            // t-chunk within block
  int q = lane >> 4;
  int n = lane & 15;
  int wbase = tc * 48;

  float4v acc[2][3];
  #pragma unroll
  for (int mt = 0; mt < 2; ++mt)
    #pragma unroll
    for (int nt = 0; nt < 3; ++nt) acc[mt][nt] = (float4v)(0.f);

  const short8* wp = (const short8*)wpk;
  #pragma unroll
  for (int s = 0; s < NSTEP; ++s) {
    int tap = s / CC;
    int c0 = (s % CC) * 32;
    short8 Ah[2], Al[2];
    #pragma unroll
    for (int mt = 0; mt < 2; ++mt) {
      int mtg = mh * 2 + mt;
      Ah[mt] = wp[((0 * NSTEP + s) * 4 + mtg) * 64 + lane];
      Al[mt] = wp[((1 * NSTEP + s) * 4 + mtg) * 64 + lane];
    }
    short8 Bh[3], Bl[3];
    #pragma unroll
    for (int nt = 0; nt < 3; ++nt) {
      int off = (wbase + nt * 16 + n + tap) * PITCH + c0 + q * 8;
      Bh[nt] = *(const short8*)&xs_hi[off];
      Bl[nt] = *(const short8*)&xs_lo[off];
    }
    #pragma unroll
    for (int mt = 0; mt < 2; ++mt) {
      #pragma unroll
      for (int nt = 0; nt < 3; ++nt) {
        acc[mt][nt] = __builtin_amdgcn_mfma_f32_16x16x32_bf16(Ah[mt], Bh[nt], acc[mt][nt], 0, 0, 0);
        acc[mt][nt] = __builtin_amdgcn_mfma_f32_16x16x32_bf16(Ah[mt], Bl[nt], acc[mt][nt], 0, 0, 0);
        acc[mt][nt] = __builtin_amdgcn_mfma_f32_16x16x32_bf16(Al[mt], Bh[nt], acc[mt][nt], 0, 0, 0);
      }
    }
  }

  float* Yp = Y + (size_t)((b * 2 + p) * H_) * FT + f * T_;
  unsigned* Yu = (unsigned*)Y + (size_t)((b * 2 + p) * H_) * FT + f * T_;
  #pragma unroll
  for (int nt = 0; nt < 3; ++nt) {
    int t = t0 + wbase + nt * 16 + n;
    if (t >= T_) continue;
    #pragma unroll
    for (int mt = 0; mt < 2; ++mt) {
      #pragma unroll
      for (int r = 0; r < 4; ++r) {
        int h = (mh * 2 + mt) * 16 + q * 4 + r;
        float v = acc[mt][nt][r] + bias[h];
        if (EPI == 0) {
          Yp[h * FT + t] = v;
        } else {
          if (EPI == 1 && p == 0) v = lrelu_f(v);
          Yu[h * FT + t] = pack_hl(v);
        }
      }
    }
  }
}

// ======== MFMA complex conv CIN2=128 K=1, branch-merged, PRO=1 cexp+trelu ====
template<int COUT2, int PRO>
__global__ __launch_bounds__(256) void k_cconv128(
    const float* __restrict__ X0a, const float* __restrict__ X1a,
    const float* __restrict__ X0b, const float* __restrict__ X1b,
    const short* __restrict__ wpka, const short* __restrict__ wpkb,
    const float* __restrict__ ata, const float* __restrict__ atb,
    const float* __restrict__ aba, const float* __restrict__ abb,
    const float* __restrict__ biasa, const float* __restrict__ biasb,
    float* __restrict__ Ya, float* __restrict__ Yb) {
  constexpr int MT = (COUT2 + 15) / 16;
  constexpr int MTW = (MT > 4) ? 4 : MT;
  constexpr int COUT = COUT2 / 2;
  constexpr int NSTEP = 4;
  constexpr int PITCH = 72;
  __shared__ short xs_hi[TW * PITCH];
  __shared__ short xs_lo[TW * PITCH];
  __shared__ float coef[6][64];
  int f = blockIdx.x;
  int y = blockIdx.y;
  int brsel = (y >= B_);
  int b = y - brsel * B_;
  const float* X0 = brsel ? X0b : X0a;
  const float* X1 = brsel ? X1b : X1a;
  const short* wpk = brsel ? wpkb : wpka;
  const float* at = brsel ? atb : ata;
  const float* ab = brsel ? abb : aba;
  const float* bias = brsel ? biasb : biasa;
  float* Y = brsel ? Yb : Ya;
  int t0 = blockIdx.z * TW;
  int tid = threadIdx.x;
  int lane = tid & 63;
  int wv = __builtin_amdgcn_readfirstlane(tid >> 6);
  int mh = wv >> 1;
  int tc = wv & 1;
  int q = lane >> 4;
  int n = lane & 15;
  int wbase = tc * 48;

  if (tid < 64) {
    int h = tid;
    coef[0][h] = at[(0 * H_ + h) * F_ + f];
    coef[1][h] = at[(1 * H_ + h) * F_ + f];
    coef[2][h] = at[(2 * H_ + h) * F_ + f];
    coef[3][h] = at[(3 * H_ + h) * F_ + f];
    coef[4][h] = ab[h * F_ + f];
    coef[5][h] = ab[(H_ + h) * F_ + f];
  }
  // targeted zero-fill: only rows with t >= T_ (tail of z=1 chunk)
  {
    int inval0 = T_ - t0;
    if (inval0 < 0) inval0 = 0;
    if (inval0 > TW) inval0 = TW;
    int nfill = (TW - inval0) * PITCH;
    for (int i = tid; i < nfill; i += 256) {
      int o = inval0 * PITCH + i;
      xs_hi[o] = 0; xs_lo[o] = 0;
    }
  }

  const float* b0r = X0 + (size_t)((b * 2 + 0) * H_) * FT + f * T_;
  const float* b0i = X0 + (size_t)((b * 2 + 1) * H_) * FT + f * T_;
  const float* b1r = X1 + (size_t)((b * 2 + 0) * H_) * FT + f * T_;
  const float* b1i = X1 + (size_t)((b * 2 + 1) * H_) * FT + f * T_;

  float4v acc[MTW][3];
  #pragma unroll
  for (int mt = 0; mt < MTW; ++mt)
    #pragma unroll
    for (int nt = 0; nt < 3; ++nt) acc[mt][nt] = (float4v)(0.f);

  const short8* wp = (const short8*)wpk;
  for (int half = 0; half < 2; ++half) {
    __syncthreads();
    for (int i = tid; i < 32 * TW; i += 256) {
      int hh = i / TW, tl = i % TW;
      int t = t0 + tl;
      if (t >= T_) continue;
      int h = half * 32 + hh;
      float xr = b0r[h * FT + t], xi = b0i[h * FT + t];
      float vr, vi;
      if (PRO == 1) {
        float er, ei;
        cexp_f(xr, xi, er, ei);
        vr = lrelu_f(er * coef[0][h] + ei * coef[1][h] + coef[4][h]);
        vi = lrelu_f(er * coef[2][h] + ei * coef[3][h] + coef[5][h]);
      } else {
        float yr = b1r[h * FT + t], yi = b1i[h * FT + t];
        float mr = xr * yr - xi * yi;
        float mi = xr * yi + xi * yr;
        vr = lrelu_f(mr * coef[0][h] + mi * coef[1][h] + coef[4][h]);
        vi = lrelu_f(mr * coef[2][h] + mi * coef[3][h] + coef[5][h]);
      }
      int cs0 = hh * 2, cs1 = hh * 2 + 1;
      short hr = f2bf(vr), hi2 = f2bf(vi);
      xs_hi[tl * PITCH + cs0] = hr;
      xs_lo[tl * PITCH + cs0] = f2bf(vr - bf2f(hr));
      xs_hi[tl * PITCH + cs1] = hi2;
      xs_lo[tl * PITCH + cs1] = f2bf(vi - bf2f(hi2));
    }
    __syncthreads();
    #pragma unroll
    for (int s2 = 0; s2 < 2; ++s2) {
      int s = half * 2 + s2;
      short8 Bh[3], Bl[3];
      #pragma unroll
      for (int nt = 0; nt < 3; ++nt) {
        int off = (wbase + nt * 16 + n) * PITCH + s2 * 32 + q * 8;
        Bh[nt] = *(const short8*)&xs_hi[off];
        Bl[nt] = *(const short8*)&xs_lo[off];
      }
      #pragma unroll
      for (int mt = 0; mt < MTW; ++mt) {
        int mtg = mh * 4 + mt;
        if (mtg >= MT) continue;
        short8 Ah = wp[((0 * NSTEP + s) * MT + mtg) * 64 + lane];
        short8 Al = wp[((1 * NSTEP + s) * MT + mtg) * 64 + lane];
        #pragma unroll
        for (int nt = 0; nt < 3; ++nt) {
          acc[mt][nt] = __builtin_amdgcn_mfma_f32_16x16x32_bf16(Ah, Bh[nt], acc[mt][nt], 0, 0, 0);
          acc[mt][nt] = __builtin_amdgcn_mfma_f32_16x16x32_bf16(Ah, Bl[nt], acc[mt][nt], 0, 0, 0);
          acc[mt][nt] = __builtin_amdgcn_mfma_f32_16x16x32_bf16(Al, Bh[nt], acc[mt][nt], 0, 0, 0);
        }
      }
    }
  }

  float* Yp = Y + (size_t)b * COUT2 * FT + f * T_;
  #pragma unroll
  for (int nt = 0; nt < 3; ++nt) {
    int t = t0 + wbase + nt * 16 + n;
    if (t >= T_) continue;
    #pragma unroll
    for (int mt = 0; mt < MTW; ++mt) {
      int mtg = mh * 4 + mt;
      if (mtg >= MT) continue;
      #pragma unroll
      for (int r = 0; r < 4; ++r) {
        int o2 = mtg * 16 + q * 4 + r;
        if (o2 >= COUT2) continue;
        int po = o2 / COUT, ho = o2 % COUT;
        float br2 = bias[ho], bi2 = bias[COUT + ho];
        float badd = (po == 0) ? br2 - bi2 : br2 + bi2;
        Yp[o2 * FT + t] = acc[mt][nt][r] + badd;
      }
    }
  }
}

// ======== MFMA complex conv, CIN2=16, K=8 (real-ified), branch-merged ========
__global__ __launch_bounds__(256) void k_cconv16(
    const float* __restrict__ Xa, const float* __restrict__ Xb,
    const short* __restrict__ wpka, const short* __restrict__ wpkb,
    const float* __restrict__ biasa, const float* __restrict__ biasb,
    float* __restrict__ Ya, float* __restrict__ Yb) {
  constexpr int MT = 8, NSTEP = 4, PITCH = 24, ROWS = TW + 7, COUT = 64, COUT2 = 128;
  __shared__ short xs_hi[ROWS * PITCH];
  __shared__ short xs_lo[ROWS * PITCH];
  int f = blockIdx.x;
  int y = blockIdx.y;
  int brsel = (y >= B_);
  int b = y - brsel * B_;
  const float* X = brsel ? Xb : Xa;
  const short* wpk = brsel ? wpkb : wpka;
  const float* bias = brsel ? biasb : biasa;
  float* Y = brsel ? Yb : Ya;
  int t0 = blockIdx.z * TW;
  int tid = threadIdx.x;

  // targeted zero-fill: only halo rows (K=8, c band unused: reads c<16=CIN)
  {
    int lo_inval = 7 - t0;
    if (lo_inval < 0) lo_inval = 0;
    int hi_start = T_ - t0 + 7;
    if (hi_start > ROWS) hi_start = ROWS;
    for (int i = tid; i < lo_inval * PITCH; i += 256) { xs_hi[i] = 0; xs_lo[i] = 0; }
    int nhi = (ROWS - hi_start) * PITCH;
    for (int i = tid; i < nhi; i += 256) {
      int o = hi_start * PITCH + i;
      xs_hi[o] = 0; xs_lo[o] = 0;
    }
  }
  __syncthreads();

  const float* Xp = X + (size_t)b * 16 * FT + f * T_;
  for (int i = tid; i < 16 * ROWS; i += 256) {
    int c = i / ROWS, rr = i % ROWS;
    int t = t0 + rr - 7;
    if (t < 0 || t >= T_) continue;
    float v = Xp[c * FT + t];
    short hi = f2bf(v);
    short lo = f2bf(v - bf2f(hi));
    xs_hi[rr * PITCH + c] = hi;
    xs_lo[rr * PITCH + c] = lo;
  }
  __syncthreads();

  int lane = tid & 63;
  int wv = __builtin_amdgcn_readfirstlane(tid >> 6);
  int mh = wv >> 1;
  int tc = wv & 1;
  int q = lane >> 4;
  int n = lane & 15;
  int wbase = tc * 48;

  float4v acc[4][3];
  #pragma unroll
  for (int mt = 0; mt < 4; ++mt)
    #pragma unroll
    for (int nt = 0; nt < 3; ++nt) acc[mt][nt] = (float4v)(0.f);

  const short8* wp = (const short8*)wpk;
  #pragma unroll
  for (int s = 0; s < NSTEP; ++s) {
    int tap = s * 2 + (q >> 1);
    int coff = (q & 1) * 8;
    short8 Bh[3], Bl[3];
    #pragma unroll
    for (int nt = 0; nt < 3; ++nt) {
      int off = (wbase + nt * 16 + n + tap) * PITCH + coff;
      Bh[nt] = *(const short8*)&xs_hi[off];
      Bl[nt] = *(const short8*)&xs_lo[off];
    }
    #pragma unroll
    for (int mt = 0; mt < 4; ++mt) {
      int mtg = mh * 4 + mt;
      short8 Ah = wp[((0 * NSTEP + s) * MT + mtg) * 64 + lane];
      short8 Al = wp[((1 * NSTEP + s) * MT + mtg) * 64 + lane];
      #pragma unroll
      for (int nt = 0; nt < 3; ++nt) {
        acc[mt][nt] = __builtin_amdgcn_mfma_f32_16x16x32_bf16(Ah, Bh[nt], acc[mt][nt], 0, 0, 0);
        acc[mt][nt] = __builtin_amdgcn_mfma_f32_16x16x32_bf16(Ah, Bl[nt], acc[mt][nt], 0, 0, 0);
        acc[mt][nt] = __builtin_amdgcn_mfma_f32_16x16x32_bf16(Al, Bh[nt], acc[mt][nt], 0, 0, 0);
      }
    }
  }

  float* Yp = Y + (size_t)b * COUT2 * FT + f * T_;
  #pragma unroll
  for (int nt = 0; nt < 3; ++nt) {
    int t = t0 + wbase + nt * 16 + n;
    if (t >= T_) continue;
    #pragma unroll
    for (int mt = 0; mt < 4; ++mt) {
      #pragma unroll
      for (int r = 0; r < 4; ++r) {
        int o2 = (mh * 4 + mt) * 16 + q * 4 + r;
        int po = o2 / COUT, ho = o2 % COUT;
        float br2 = bias[ho], bi2 = bias[COUT + ho];
        float badd = (po == 0) ? br2 - bi2 : br2 + bi2;
        Yp[o2 * FT + t] = acc[mt][nt][r] + badd;
      }
    }
  }
}

// ---------------- cExp from packed u32 hi/lo input (branch-merged) -----------
__global__ void k_cexp_pk(const unsigned* __restrict__ Xa, const unsigned* __restrict__ Xb,
                          float* __restrict__ Ya, float* __restrict__ Yb) {
  int i = blockIdx.x * blockDim.x + threadIdx.x;
  if (i >= 2 * B_ * H_ * FT) return;
  int brsel = (i >= B_ * H_ * FT);
  int j = i - brsel * (B_ * H_ * FT);
  const unsigned* X = brsel ? Xb : Xa;
  float* Y = brsel ? Yb : Ya;
  int b = j / (H_ * FT);
  int r = j % (H_ * FT);
  size_t i0 = (size_t)(b * 2) * H_ * FT + r;
  size_t i1 = i0 + (size_t)H_ * FT;
  unsigned v0 = X[i0], v1 = X[i1];
  float tr = unpack_hl(v0);
  float ti = unpack_hl(v1);
  float er, ei;
  cexp_f(tr, ti, er, ei);
  Y[i0] = er;
  Y[i1] = ei;
}

__global__ void k_td1(const float* __restrict__ ts, const float* __restrict__ t8,
                      float* __restrict__ td1) {
  int i = blockIdx.x * blockDim.x + threadIdx.x;
  if (i >= B_ * 2 * FT) return;
  int bp = i / FT; int r = i % FT;
  const float* a = ts + bp * C_IN * FT + r;
  const float* c2 = t8 + bp * C_IN * FT + r;
  float acc = 0.f;
  #pragma unroll
  for (int c = 0; c < C_IN; ++c) acc += a[c * FT] - c2[c * FT];
  td1[i] = acc * (1.f / C_IN);
}

// ------------- fuse: cconv(concat) -> tgate -> blend -------------
__global__ void k_fuse(const float* __restrict__ tl1, const float* __restrict__ tl2,
                       const float* __restrict__ td1, const float* __restrict__ td2,
                       const float* __restrict__ cw, const float* __restrict__ cwb,
                       const float* __restrict__ fgt, const float* __restrict__ fgb,
                       float* __restrict__ td) {
  int i = blockIdx.x * blockDim.x + threadIdx.x;
  if (i >= B_ * FT) return;
  int b = i / FT; int r = i % FT; int f = r / T_;
  const float* x1r = tl1 + (b * 2) * H_ * FT + r;
  const float* x1i = x1r + H_ * FT;
  const float* x2r = tl2 + (b * 2) * H_ * FT + r;
  const float* x2i = x2r + H_ * FT;
  float fr = 0.f, fi = 0.f;
  for (int c = 0; c < H_; ++c) {
    float w1r = cw[c], w2r = cw[H_ + c], w1i = cw[2 * H_ + c], w2i = cw[3 * H_ + c];
    float a1r = x1r[c * FT], a1i = x1i[c * FT];
    float a2r = x2r[c * FT], a2i = x2i[c * FT];
    fr += w1r * a1r - w1i * a1i + w2r * a2r - w2i * a2i;
    fi += w1r * a1i + w1i * a1r + w2r * a2i + w2i * a2r;
  }
  fr += cwb[0] - cwb[1];
  fi += cwb[0] + cwb[1];
  float t00 = fgt[f], t01 = fgt[F_ + f], t10 = fgt[2 * F_ + f], t11 = fgt[3 * F_ + f];
  float gr = sigmoid_f(fr * t00 + fi * t01 + fgb[f]);
  float gi = sigmoid_f(fr * t10 + fi * t11 + fgb[F_ + f]);
  float gg = gr * gi + (1.f - gr) * (1.f - gi);
  int i0 = (b * 2) * FT + r, i1 = i0 + FT;
  td[i0] = td1[i0] * gg + td2[i0] * (1.f - gg);
  td[i1] = td1[i1] * gg + td2[i1] * (1.f - gg);
}

// ------------- iSTFT frames: folded rotation inverse DFT -------------
__global__ __launch_bounds__(320) void k_iframes(const float* __restrict__ sp,
                                                 float* __restrict__ frames) {
  __shared__ float Xr[F_], Xi[F_];
  int blk = blockIdx.x;
  int t = blk % T_;
  int b = blk / T_;
  int tid = threadIdx.x;
  for (int i = tid; i < F_; i += 320) {
    Xr[i] = sp[(b * 2 + 0) * FT + i * T_ + t];
    Xi[i] = sp[(b * 2 + 1) * FT + i * T_ + t];
  }
  __syncthreads();
  int n = tid;
  if (n <= 256) {
    float sd, cd;
    sincosf((PI2 / NFFT) * n, &sd, &cd);
    float cs = cd, sn = sd;
    float ac = 0.f, as = 0.f;
    for (int f = 1; f < 256; ++f) {
      ac += Xr[f] * cs;
      as += Xi[f] * sn;
      float t2 = cs * cd - sn * sd;
      sn = sn * cd + cs * sd;
      cs = t2;
    }
    float base = Xr[0] + Xr[256] * (1.f - 2.f * (n & 1));
    float win = 0.5f - 0.5f * cd;
    float scale = win * (1.f / NFFT);
    float* fr = frames + (size_t)(b * T_ + t) * NFFT;
    fr[n] = (base + 2.f * ac - 2.f * as) * scale;
    if (n >= 1 && n <= 255)
      fr[NFFT - n] = (base + 2.f * ac + 2.f * as) * scale;
  }
}

// ------------- overlap-add + wsum normalize + center-crop -------------
__global__ void k_ola(const float* __restrict__ frames, float* __restrict__ out) {
  int i = blockIdx.x * blockDim.x + threadIdx.x;
  if (i >= B_ * LEN) return;
  int b = i / LEN; int j = i % LEN;
  int p = j + PADL;
  int t0 = p / HOP; int n0 = p - t0 * HOP;
  float acc = 0.f, wsum = 0.f;
  if (t0 < T_) {
    acc += frames[(b * T_ + t0) * NFFT + n0];
    float w = 0.5f - 0.5f * __cosf((PI2 / NFFT) * n0);
    wsum += w * w;
  }
  int t1 = t0 - 1, n1 = n0 + HOP;
  if (t1 >= 0 && t1 < T_) {
    acc += frames[(b * T_ + t1) * NFFT + n1];
    float w = 0.5f - 0.5f * __cosf((PI2 / NFFT) * n1);
    wsum += w * w;
  }
  out[i] = acc / fmaxf(wsum, 1e-11f);
}

extern "C" void kernel_launch(void* const* d_in, const int* in_sizes, int n_in,
                              void* d_out, int out_size, void* d_ws, size_t ws_size,
                              hipStream_t stream) {
  const float* mix   = (const float*)d_in[0];
  const float* fs_w  = (const float*)d_in[1];
  const float* fs_b  = (const float*)d_in[2];
  const float* fr_w  = (const float*)d_in[3];
  const float* fr_b  = (const float*)d_in[4];
  const float* c1r_w = (const float*)d_in[5];
  const float* c1r_b = (const float*)d_in[6];
  const float* c1i_w = (const float*)d_in[7];
  const float* c1i_b = (const float*)d_in[8];
  const float* c1_w  = (const float*)d_in[9];
  const float* c1_b  = (const float*)d_in[10];
  const float* c2r_w = (const float*)d_in[11];
  const float* c2r_b = (const float*)d_in[12];
  const float* c2i_w = (const float*)d_in[13];
  const float* c2i_b = (const float*)d_in[14];
  const float* c2_w  = (const float*)d_in[15];
  const float* c2_b  = (const float*)d_in[16];
  const float* a1_t  = (const float*)d_in[17];
  const float* a1_b  = (const float*)d_in[18];
  const float* a2_t  = (const float*)d_in[19];
  const float* a2_b  = (const float*)d_in[20];
  const float* c3r_w = (const float*)d_in[21];
  const float* c3r_b = (const float*)d_in[22];
  const float* c3i_w = (const float*)d_in[23];
  const float* c3i_b = (const float*)d_in[24];
  const float* c3_w  = (const float*)d_in[25];
  const float* c3_b  = (const float*)d_in[26];
  const float* c4r_w = (const float*)d_in[27];
  const float* c4r_b = (const float*)d_in[28];
  const float* c4i_w = (const float*)d_in[29];
  const float* c4i_b = (const float*)d_in[30];
  const float* c4_w  = (const float*)d_in[31];
  const float* c4_b  = (const float*)d_in[32];
  const float* a3_t  = (const float*)d_in[33];
  const float* a3_b  = (const float*)d_in[34];
  const float* a4_t  = (const float*)d_in[35];
  const float* a4_b  = (const float*)d_in[36];
  const float* f1_w  = (const float*)d_in[37];
  const float* f1_b  = (const float*)d_in[38];
  const float* f2_w  = (const float*)d_in[39];
  const float* f2_b  = (const float*)d_in[40];
  const float* cw_w  = (const float*)d_in[41];
  const float* cw_b  = (const float*)d_in[42];
  const float* fg_t  = (const float*)d_in[43];
  const float* fg_b  = (const float*)d_in[44];

  const size_t S8 = (size_t)B_ * 2 * C_IN * FT;
  const size_t SH = (size_t)B_ * 2 * H_ * FT;
  const size_t S1 = (size_t)B_ * 2 * FT;
  float* ws  = (float*)d_ws;
  float* ts0 = ws;
  float* ts  = ts0 + S8;
  float* A1  = ts + S8;
  float* A2  = A1 + SH;
  float* Bb  = A2 + SH;
  float* Cc  = Bb + SH;
  float* td1 = Cc + SH;
  float* td2 = td1 + S1;
  float* tdf = td2 + S1;
  float* tdr = tdf + S1;
  float* s8  = ts0;
  float* frames = ts0;

  short* wtail = (short*)(tdr + S1);
  constexpr int SZ_C8K1   = 2 * 1  * 4 * 64 * 8;
  constexpr int SZ_C64K1  = 2 * 2  * 4 * 64 * 8;
  constexpr int SZ_C64K8  = 2 * 16 * 4 * 64 * 8;
  constexpr int SZ_CC128  = 2 * 4  * 8 * 64 * 8;
  constexpr int SZ_CF     = 2 * 4  * 1 * 64 * 8;
  constexpr int SZ_SM     = 2 * 16 * 33 * 64 * 8;   // stft+mix fused matrix
  short* w_c1r = wtail;
  short* w_c1i = w_c1r + SZ_C8K1;
  short* w_c2r = w_c1i + SZ_C64K1;
  short* w_c2i = w_c2r + SZ_C64K8;
  short* w_c3r = w_c2i + SZ_C64K8;
  short* w_c3i = w_c3r + SZ_C8K1;
  short* w_c4r = w_c3i + SZ_C64K1;
  short* w_c4i = w_c4r + SZ_C64K8;
  short* w_cc1 = w_c4i + SZ_C64K8;
  short* w_cc2 = w_cc1 + SZ_CC128;
  short* w_cc3 = w_cc2 + SZ_CC128;
  short* w_cc4 = w_cc3 + SZ_CC128;
  short* w_cf1 = w_cc4 + SZ_CC128;
  short* w_cf2 = w_cf1 + SZ_CF;
  short* w_sm  = w_cf2 + SZ_CF;
  short* mhi   = w_sm + SZ_SM;
  short* mlo   = mhi + (size_t)B_ * C_IN * LEN;

  const int nH = B_ * H_ * FT;
  const int nP = B_ * FT;
  const dim3 mrgrid(F_, 2 * B_ * 2, 2);  // merged real convs: (f, br*(b*2+p), t-half)
  const dim3 mcgrid(F_, 2 * B_, 2);      // merged complex convs: (f, br*b, t-half)
  const dim3 cgrid(F_, B_, 2);           // single-branch complex convs

  k_repack_all<<<dim3(256, 14), 256, 0, stream>>>(
      c1r_w, c1i_w, c2r_w, c2i_w, c3r_w, c3i_w, c4r_w, c4i_w,
      c1_w, c2_w, c3_w, c4_w, f1_w, f2_w,
      w_c1r, w_c1i, w_c2r, w_c2i, w_c3r, w_c3i, w_c4r, w_c4i,
      w_cc1, w_cc2, w_cc3, w_cc4, w_cf1, w_cf2);

  // fused STFT + frequency mixing (M = fs_w x win*DFT, then MFMA GEMM)
  k_mixsplit<<<(B_ * C_IN * LEN / 4 + 255) / 256, 256, 0, stream>>>(mix, mhi, mlo);
  k_mixdft<<<dim3(528, 2), 256, 0, stream>>>(fs_w, w_sm);
  k_stftmix<<<dim3(9, 16, 4), 256, 0, stream>>>(mhi, mlo, w_sm, fs_b, ts);

  // ---- both branches, co-scheduled layer by layer ----
  k_conv_mfma<C_IN, 1, 2, 1><<<mrgrid, 256, 0, stream>>>(
      ts, ts, w_c1r, w_c3r, c1r_b, c3r_b, A1, A2);                 // cLog+c{1,3}r
  k_conv_mfma<H_, 1, 3, 0><<<mrgrid, 256, 0, stream>>>(
      A1, A2, w_c1i, w_c3i, c1i_b, c3i_b, Bb, Cc);                 // +c{1,3}i
  k_cconv128<128, 1><<<mcgrid, 256, 0, stream>>>(
      Bb, Bb, Cc, Cc, w_cc1, w_cc3, a1_t, a3_t, a1_b, a3_b,
      c1_b, c3_b, A1, A2);                                          // cexp+trelu+c{1,3}
  k_conv_mfma<H_, 8, 2, 1><<<mrgrid, 256, 0, stream>>>(
      A1, A2, w_c2r, w_c4r, c2r_b, c4r_b, Bb, Cc);                 // cLog+c{2,4}r
  k_conv_mfma<H_, 8, 3, 2><<<mrgrid, 256, 0, stream>>>(
      Bb, Cc, w_c2i, w_c4i, c2i_b, c4i_b, A1, A2);                 // +c{2,4}i (packed)
  k_cexp_pk<<<(2 * nH + 255) / 256, 256, 0, stream>>>(
      (const unsigned*)A1, (const unsigned*)A2, Bb, Cc);           // Bb=tl1, Cc=tl2
  k_cconv16<<<mcgrid, 256, 0, stream>>>(
      ts, ts, w_cc2, w_cc4, c2_b, c4_b, A1, A2);                   // tc1->A1, tc2->A2
  k_cconv128<16, 2><<<cgrid, 256, 0, stream>>>(
      Bb, A1, Bb, A1, w_cf1, w_cf1, a2_t, a2_t, a2_b, a2_b,
      f1_b, f1_b, s8, s8);                                          // cmul+trelu+f1
  k_td1<<<(B_ * 2 * FT + 255) / 256, 256, 0, stream>>>(ts, s8, td1);
  k_cconv128<2, 2><<<cgrid, 256, 0, stream>>>(
      Cc, A2, Cc, A2, w_cf2, w_cf2, a4_t, a4_t, a4_b, a4_b,
      f2_b, f2_b, td2, td2);                                        // cmul+trelu+f2

  // ---- fuse + unmix + iSTFT ----
  k_fuse<<<(nP + 255) / 256, 256, 0, stream>>>(Bb, Cc, td1, td2, cw_w, cw_b, fg_t, fg_b, tdf);
  k_fmix<1><<<dim3(F_, B_), 192, 0, stream>>>(tdf, fr_w, fr_b, tdr);
  k_iframes<<<B_ * T_, 320, 0, stream>>>(tdr, frames);
  k_ola<<<(B_ * LEN + 255) / 256, 256, 0, stream>>>(frames, (float*)d_out);
}